// Round 11
// baseline (1137.245 us; speedup 1.0000x reference)
//
#include <hip/hip_runtime.h>

typedef __attribute__((ext_vector_type(8))) short short8;
typedef __attribute__((ext_vector_type(4))) float f32x4;
typedef __attribute__((ext_vector_type(4))) unsigned short us4v;
typedef unsigned short ushort_t;
typedef unsigned int uint_t;

#define BB 4
#define T_ 1024
#define T2 2048
#define DD 256
#define DIN 512
#define NMARK 64
#define LNEPS 1e-5f
#define KDIV (-0.035977892078032f)

__device__ __forceinline__ ushort_t f2bf(float f) {
  unsigned int u = __float_as_uint(f);
  unsigned int r = (u + 0x7fffu + ((u >> 16) & 1u)) >> 16;
  return (ushort_t)r;
}
__device__ __forceinline__ uint_t pack2(float a, float b) {
  return (uint_t)f2bf(a) | ((uint_t)f2bf(b) << 16);
}
__device__ __forceinline__ uint_t cvtpk(float lo, float hi) {
  uint_t r;
  asm("v_cvt_pk_bf16_f32 %0, %1, %2" : "=v"(r) : "v"(lo), "v"(hi));
  return r;
}

typedef const __attribute__((address_space(1))) unsigned int* as1cu32;
typedef __attribute__((address_space(3))) unsigned int* as3u32;
__device__ __forceinline__ void async_copy16(const void* g, void* l) {
  __builtin_amdgcn_global_load_lds((as1cu32)g, (as3u32)l, 16, 0, 0);
}

// ---------- init: type/time embeddings -> Xh (bf16), Cur = 0 ----------
__global__ __launch_bounds__(256) void k_init(const float* __restrict__ ev,
                                              const float* __restrict__ tm,
                                              const float* __restrict__ Wt,
                                              const float* __restrict__ bt,
                                              ushort_t* __restrict__ Xh,
                                              float* __restrict__ Cur) {
  const int btq = blockIdx.x;
  const int b = btq >> 10;
  const int t = btq & 1023;
  const int d = threadIdx.x;
  __shared__ float evs[NMARK];
  if (d < NMARK) evs[d] = ev[(size_t)btq * NMARK + d];
  __syncthreads();
  float s = bt[d];
#pragma unroll
  for (int m = 0; m < NMARK; ++m) s += evs[m] * Wt[m * DD + d];
  const float te_type = tanhf(s);
  const float tv = tm[btq];
  const int i = d >> 1;
  const float dv = expf((float)(2 * i) * KDIV);
  const float ang = tv * dv;
  const float te_time = (d & 1) ? cosf(ang) : sinf(ang);
  ushort_t* Xb = Xh + (size_t)b * T2 * DIN;
  const ushort_t tt = f2bf(te_time);
  Xb[(size_t)t * DIN + d] = f2bf(te_type);
  Xb[(size_t)t * DIN + DD + d] = tt;
  Xb[(size_t)(T_ + t) * DIN + d] = 0;
  Xb[(size_t)(T_ + t) * DIN + DD + d] = tt;
  Cur[((size_t)b * T_ + t) * DD + d] = 0.0f;
}

// ---------- weight transpose: W[hl][k][n] f32 -> WT[mat][n][k] bf16 ----------
__global__ __launch_bounds__(256) void k_transW(const float* __restrict__ Wq,
                                                const float* __restrict__ Wk,
                                                const float* __restrict__ Wv,
                                                ushort_t* __restrict__ WT) {
  const int mi = blockIdx.x;
  const int wsel = mi / 12, hl = mi % 12;
  const float* W = ((wsel == 0) ? Wq : (wsel == 1) ? Wk : Wv) + (size_t)hl * DIN * DD;
  const int t = blockIdx.y;
  const int k0 = (t >> 2) * 64, n0 = (t & 3) * 64;
  __shared__ float Ts[64][65];
  const int tid = threadIdx.x;
#pragma unroll
  for (int i = 0; i < 16; ++i) {
    const int idx = tid + i * 256;
    const int r = idx >> 6, c = idx & 63;
    Ts[r][c] = W[(size_t)(k0 + r) * DD + n0 + c];
  }
  __syncthreads();
  ushort_t* D = WT + (size_t)mi * DD * DIN;
#pragma unroll
  for (int i = 0; i < 16; ++i) {
    const int idx = tid + i * 256;
    const int rn = idx >> 6, ck = idx & 63;
    D[(size_t)(n0 + rn) * DIN + k0 + ck] = f2bf(Ts[ck][rn]);
  }
}

// ---------- QKV GEMM; V written pi32-permuted into 32-wide TILES ----------
// VTt[b][tile32(64)][d(256)][32] bf16: 16KB contiguous per KV-tile.
__global__ __launch_bounds__(256) void k_qkv(const ushort_t* __restrict__ Xh,
                                             const ushort_t* __restrict__ WT,
                                             const float* __restrict__ bq,
                                             const float* __restrict__ bk,
                                             const float* __restrict__ bv,
                                             ushort_t* __restrict__ Qh,
                                             ushort_t* __restrict__ Kh,
                                             ushort_t* __restrict__ VTt,
                                             int hl) {
  const int m0 = blockIdx.x * 128;
  const int n0 = blockIdx.y * 128;
  const int wsel = blockIdx.z;
  const ushort_t* Bt = WT + ((size_t)(wsel * 12 + hl)) * DD * DIN + (size_t)n0 * DIN;
  const float* bias = (wsel == 0) ? bq : (wsel == 1) ? bk : bv;

  __shared__ ushort_t As[128 * 64];
  __shared__ ushort_t Bs[128 * 64];
  const int tid = threadIdx.x;
  const int w = tid >> 6, lane = tid & 63;
  const int wr = w >> 1, wc = w & 1;
  const int lr = lane & 15, kg = lane >> 4;

  f32x4 acc[4][4];
  const f32x4 z4 = {0.f, 0.f, 0.f, 0.f};
#pragma unroll
  for (int a = 0; a < 4; ++a)
#pragma unroll
    for (int c = 0; c < 4; ++c) acc[a][c] = z4;

  for (int k0 = 0; k0 < DIN; k0 += 64) {
#pragma unroll
    for (int i = 0; i < 4; ++i) {
      const int idx = tid + i * 256;
      const int row = idx >> 3, ch = idx & 7;
      const int db = row * 128 + ((ch * 16) ^ ((row & 7) << 4));
      uint4 va = *(const uint4*)&Xh[(size_t)(m0 + row) * DIN + k0 + ch * 8];
      *(uint4*)((char*)As + db) = va;
      uint4 vb = *(const uint4*)&Bt[(size_t)row * DIN + k0 + ch * 8];
      *(uint4*)((char*)Bs + db) = vb;
    }
    __syncthreads();
#pragma unroll
    for (int kk = 0; kk < 2; ++kk) {
      short8 af[4], bfr[4];
      const int cb = kk * 64 + kg * 16;
#pragma unroll
      for (int mi = 0; mi < 4; ++mi) {
        const int row = wr * 64 + mi * 16 + lr;
        af[mi] = *(const short8*)((const char*)As + row * 128 + (cb ^ ((row & 7) << 4)));
      }
#pragma unroll
      for (int ni = 0; ni < 4; ++ni) {
        const int row = wc * 64 + ni * 16 + lr;
        bfr[ni] = *(const short8*)((const char*)Bs + row * 128 + (cb ^ ((row & 7) << 4)));
      }
#pragma unroll
      for (int mi = 0; mi < 4; ++mi)
#pragma unroll
        for (int ni = 0; ni < 4; ++ni)
          acc[mi][ni] = __builtin_amdgcn_mfma_f32_16x16x32_bf16(af[mi], bfr[ni], acc[mi][ni], 0, 0, 0);
    }
    __syncthreads();
  }

  if (wsel < 2) {
    ushort_t* C = (wsel == 0) ? Qh : Kh;
#pragma unroll
    for (int mi = 0; mi < 4; ++mi)
#pragma unroll
      for (int ni = 0; ni < 4; ++ni) {
        const int col = n0 + wc * 64 + ni * 16 + lr;
        const float bcol = bias[col];
        const int rbase = m0 + wr * 64 + mi * 16 + kg * 4;
#pragma unroll
        for (int r = 0; r < 4; ++r)
          C[(size_t)(rbase + r) * DD + col] = f2bf(acc[mi][ni][r] + bcol);
      }
  } else {
    const int b2 = m0 >> 11;
    const int t0q = m0 & 2047;
#pragma unroll
    for (int mi = 0; mi < 4; ++mi)
#pragma unroll
      for (int ni = 0; ni < 4; ++ni) {
        const int col = n0 + wc * 64 + ni * 16 + lr;
        const float bcol = bias[col];
        const int t32 = (t0q >> 5) + wr * 2 + (mi >> 1);
        const int jloc = kg * 8 + (mi & 1) * 4;
        uint2 pk;
        pk.x = pack2(acc[mi][ni][0] + bcol, acc[mi][ni][1] + bcol);
        pk.y = pack2(acc[mi][ni][2] + bcol, acc[mi][ni][3] + bcol);
        *(uint2*)(VTt + ((size_t)(b2 * 64 + t32)) * (DD * 32) + col * 32 + jloc) = pk;
      }
  }
}

// ---------- flash: 1024 one-wave blocks, 8 q-rows each, barrier-free ----------
// bx: c = 127-(bx>>3) (heavy first), b = (bx>>1)&3, hb = bx&1.
// LDS: K dbuf 2x16KB | V 16KB @32768. Sync: manual vmcnt only (single wave).
__global__ __launch_bounds__(64) void k_flash(const ushort_t* __restrict__ Qh,
                                              const ushort_t* __restrict__ Kh,
                                              const ushort_t* __restrict__ VTt,
                                              float* __restrict__ Cur,
                                              ushort_t* __restrict__ Xh,
                                              float* __restrict__ out,
                                              const float* __restrict__ nw,
                                              const float* __restrict__ nb,
                                              int lastLayer, int h) {
  __shared__ char lds[49152];
  const int bx = blockIdx.x;
  const int hb = bx & 1;
  const int b = (bx >> 1) & 3;
  const int c = 127 - (bx >> 3);
  const int t0 = c * 8;
  const int ntc = (c >> 2) + 1;
  const int nt = ntc + hb;
  const int dt = 32 + (c >> 2);
  const int off0 = (c & 3) * 8;

  const int lane = threadIdx.x;
  const int kg = lane >> 4, lr = lane & 15;
  const int lrow = lr & 7;
  const bool live = lr < 8;
  const int t = t0 + lr;               // masking value (only meaningful when live)
  const int tq = t0 + lrow;            // clamped addressing row
  const int r0 = (hb ? T_ : 0) + tq;
  const size_t bT2 = (size_t)b * T2;

  short8 qf[8];
  {
    const ushort_t* qb = Qh + (bT2 + r0) * DD + kg * 8;
#pragma unroll
    for (int kk = 0; kk < 8; ++kk) qf[kk] = *(const short8*)(qb + kk * 32);
  }

  const f32x4 z4 = {0.f, 0.f, 0.f, 0.f};
  f32x4 acc_o[16];
#pragma unroll
  for (int db = 0; db < 16; ++db) acc_o[db] = z4;
  float m_run = -1e30f, l_run = 0.f;

#define STAGE_K(BUF, TILE)                                                               \
  {                                                                                      \
    const int _t = (TILE);                                                               \
    _Pragma("unroll") for (int s = 0; s < 16; ++s) {                                     \
      const int row2 = s * 2 + (lane >> 5);                                              \
      const int cc2 = lane & 31;                                                         \
      async_copy16((const char*)Kh + ((bT2 + _t * 32 + row2) * DD) * 2 +                 \
                       ((cc2 * 16) ^ ((row2 & 7) << 4)),                                 \
                   lds + (BUF) * 16384 + s * 1024);                                      \
    }                                                                                    \
  }
#define STAGE_V(TILE)                                                                    \
  {                                                                                      \
    const ushort_t* _vt = VTt + ((size_t)(b * 64 + (TILE))) * 8192;                      \
    _Pragma("unroll") for (int s = 0; s < 16; ++s) {                                     \
      async_copy16((const char*)_vt + s * 1024 + lane * 16, lds + 32768 + s * 1024);     \
    }                                                                                    \
  }

  STAGE_K(0, 0);

  union U8 { uint4 u; short8 s; };

  for (int kt = 0; kt < nt; ++kt) {
    const int tile = (kt < ntc) ? kt : dt;
    const bool isDiag = (kt >= ntc);

    asm volatile("s_waitcnt vmcnt(0)" ::: "memory");   // K(kt) resident
    __builtin_amdgcn_sched_barrier(0);

    STAGE_V(tile);
    if (kt + 1 < nt) STAGE_K((kt + 1) & 1, (kt + 1 < ntc) ? (kt + 1) : dt);

    // QK^T (swapped): S^T[j = tile*32 + jb*16 + kg*4 + r][q = lr]
    const char* KsC = lds + (kt & 1) * 16384;
    f32x4 sa[2];
    __builtin_amdgcn_s_setprio(1);
#pragma unroll
    for (int jb = 0; jb < 2; ++jb) {
      sa[jb] = z4;
      const int rowj = jb * 16 + lr;
      const int base = rowj * 512;
      const int swj = (rowj & 7) << 4;
#pragma unroll
      for (int kk = 0; kk < 8; ++kk) {
        short8 kf = *(const short8*)(KsC + base + ((kk * 64 + kg * 16) ^ swj));
        sa[jb] = __builtin_amdgcn_mfma_f32_16x16x32_bf16(kf, qf[kk], sa[jb], 0, 0, 0);
      }
    }
    __builtin_amdgcn_s_setprio(0);

    // mask + scale + online softmax with defer-max (wave-uniform branch)
    float sv[8];
    float tmax = -1e30f;
#pragma unroll
    for (int jb = 0; jb < 2; ++jb)
#pragma unroll
      for (int r = 0; r < 4; ++r) {
        const int jl = jb * 16 + kg * 4 + r;
        const bool valid = live && (isDiag ? (jl == off0 + lr) : ((tile * 32 + jl) < t));
        const float x = valid ? sa[jb][r] * 0.0625f : -1e30f;
        sv[jb * 4 + r] = x;
        tmax = fmaxf(tmax, x);
      }
    tmax = fmaxf(tmax, __shfl_xor(tmax, 16, 64));
    tmax = fmaxf(tmax, __shfl_xor(tmax, 32, 64));
    if (tmax > m_run + 8.0f) {          // rescale only on significant max growth
      const float fac = __expf(m_run - tmax);
      m_run = tmax;
      l_run *= fac;
#pragma unroll
      for (int db = 0; db < 16; ++db) acc_o[db] *= fac;
    }
    float p[8];
    float psum = 0.f;
#pragma unroll
    for (int e = 0; e < 8; ++e) {
      const float pe = (sv[e] > -1e29f) ? __expf(sv[e] - m_run) : 0.0f;
      p[e] = pe;
      psum += pe;
    }
    psum += __shfl_xor(psum, 16, 64);
    psum += __shfl_xor(psum, 32, 64);
    l_run += psum;

    U8 pf;
    pf.u.x = cvtpk(p[0], p[1]);
    pf.u.y = cvtpk(p[2], p[3]);
    pf.u.z = cvtpk(p[4], p[5]);
    pf.u.w = cvtpk(p[6], p[7]);

    if (kt + 1 < nt) {
      asm volatile("s_waitcnt vmcnt(16)" ::: "memory");  // V done; next-K still flying
    } else {
      asm volatile("s_waitcnt vmcnt(0)" ::: "memory");
    }
    __builtin_amdgcn_sched_barrier(0);

    // PV: O^T += V^T * P^T (K=32), V from LDS pi32 layout
    const char* VsC = lds + 32768;
    __builtin_amdgcn_s_setprio(1);
#pragma unroll
    for (int db = 0; db < 16; ++db) {
      U8 vf;
      vf.u = *(const uint4*)(VsC + (db * 16 + lr) * 64 + kg * 16);
      acc_o[db] = __builtin_amdgcn_mfma_f32_16x16x32_bf16(vf.s, pf.s, acc_o[db], 0, 0, 0);
    }
    __builtin_amdgcn_s_setprio(0);
  }
#undef STAGE_K
#undef STAGE_V

  // ---------- epilogue (wave-local; live lanes only store) ----------
  const float oinv = 1.0f / l_run;   // t==0 (top): l==0 -> store skipped

  if (!hb) {
    if (live && t != 0) {
      ushort_t* xp = Xh + (bT2 + t) * DIN + kg * 4;
#pragma unroll
      for (int db = 0; db < 16; ++db) {
        us4v o;
#pragma unroll
        for (int r = 0; r < 4; ++r) o[r] = f2bf(acc_o[db][r] * oinv);
        *(us4v*)(xp + db * 16) = o;
      }
    }
  } else {
    float* cp = Cur + ((size_t)b * T_ + tq) * DD + kg * 4;
    float s1 = 0.f, s2 = 0.f;
#pragma unroll
    for (int db = 0; db < 16; ++db) {
      f32x4 c4 = *(const f32x4*)(cp + db * 16);
#pragma unroll
      for (int r = 0; r < 4; ++r) {
        const float x = tanhf(acc_o[db][r] * oinv) + c4[r];
        acc_o[db][r] = x;
        s1 += x;
        s2 += x * x;
      }
    }
    s1 += __shfl_xor(s1, 16, 64); s1 += __shfl_xor(s1, 32, 64);
    s2 += __shfl_xor(s2, 16, 64); s2 += __shfl_xor(s2, 32, 64);
    const float mean = s1 * (1.0f / 256.0f);
    const float var = s2 * (1.0f / 256.0f) - mean * mean;
    const float rinv = rsqrtf(var + LNEPS);
    if (live) {
      ushort_t* xp = Xh + (bT2 + T_ + t) * DIN + kg * 4;
      if (lastLayer) {
        float* op = out + ((size_t)b * T_ + t) * (DD * 4) + h * DD + kg * 4;
        const us4v zz = {0, 0, 0, 0};
        const f32x4 zf = {0.f, 0.f, 0.f, 0.f};
#pragma unroll
        for (int db = 0; db < 16; ++db) {
          f32x4 w4 = *(const f32x4*)&nw[db * 16 + kg * 4];
          f32x4 b4 = *(const f32x4*)&nb[db * 16 + kg * 4];
          f32x4 y;
#pragma unroll
          for (int r = 0; r < 4; ++r) y[r] = (acc_o[db][r] - mean) * rinv * w4[r] + b4[r];
          *(f32x4*)(op + db * 16) = y;
          *(f32x4*)(cp + db * 16) = zf;
          *(us4v*)(xp + db * 16) = zz;
        }
      } else {
#pragma unroll
        for (int db = 0; db < 16; ++db) {
          f32x4 w4 = *(const f32x4*)&nw[db * 16 + kg * 4];
          f32x4 b4 = *(const f32x4*)&nb[db * 16 + kg * 4];
          f32x4 y;
          us4v yh;
#pragma unroll
          for (int r = 0; r < 4; ++r) {
            y[r] = (acc_o[db][r] - mean) * rinv * w4[r] + b4[r];
            yh[r] = f2bf(y[r]);
          }
          *(f32x4*)(cp + db * 16) = y;
          *(us4v*)(xp + db * 16) = yh;
        }
      }
    }
  }

  // ---------- row0 mean-V (4 heaviest TOP blocks per batch; start first) ----------
  if (!hb && c >= 124) {
    const int col = ((127 - c) << 6) + lane;
    float s = 0.f;
    for (int tl = 0; tl < 64; ++tl) {
      const ushort_t* vp = VTt + ((size_t)(b * 64 + tl)) * 8192 + col * 32;
#pragma unroll
      for (int j = 0; j < 32; j += 8) {
        uint4 v = *(const uint4*)(vp + j);
        const uint_t vs[4] = {v.x, v.y, v.z, v.w};
#pragma unroll
        for (int q = 0; q < 4; ++q) {
          s += __uint_as_float(vs[q] << 16);
          s += __uint_as_float(vs[q] & 0xffff0000u);
        }
      }
    }
    Xh[bT2 * DIN + col] = f2bf(s * (1.0f / 2048.0f));
  }
}

extern "C" void kernel_launch(void* const* d_in, const int* in_sizes, int n_in,
                              void* d_out, int out_size, void* d_ws, size_t ws_size,
                              hipStream_t stream) {
  const float* ev = (const float*)d_in[0];
  const float* tm = (const float*)d_in[1];
  const float* Wt = (const float*)d_in[3];
  const float* bt = (const float*)d_in[4];
  const float* Wq = (const float*)d_in[5];
  const float* bq = (const float*)d_in[6];
  const float* Wk = (const float*)d_in[7];
  const float* bk = (const float*)d_in[8];
  const float* Wv = (const float*)d_in[9];
  const float* bv = (const float*)d_in[10];
  const float* nw = (const float*)d_in[11];
  const float* nb = (const float*)d_in[12];
  float* out = (float*)d_out;

  char* p = (char*)d_ws;
  ushort_t* Xh  = (ushort_t*)p; p += (size_t)BB * T2 * DIN * 2;   // 8.39 MB
  ushort_t* Qh  = (ushort_t*)p; p += (size_t)BB * T2 * DD * 2;    // 4.19 MB
  ushort_t* Kh  = (ushort_t*)p; p += (size_t)BB * T2 * DD * 2;
  ushort_t* VTt = (ushort_t*)p; p += (size_t)BB * T2 * DD * 2;    // pi32-tiled V
  float* Cur    = (float*)p;    p += (size_t)BB * T_ * DD * 4;    // 4.19 MB
  ushort_t* WT  = (ushort_t*)p;                                   // 9.44 MB

  k_init<<<BB * T_, 256, 0, stream>>>(ev, tm, Wt, bt, Xh, Cur);
  k_transW<<<dim3(36, 32), 256, 0, stream>>>(Wq, Wk, Wv, WT);

  for (int h = 0; h < 4; ++h) {
    for (int l = 0; l < 3; ++l) {
      const int hl = h * 3 + l;
      const size_t boff = (size_t)hl * DD;
      k_qkv<<<dim3(64, 2, 3), 256, 0, stream>>>(Xh, WT, bq + boff, bk + boff, bv + boff,
                                                Qh, Kh, VTt, hl);
      k_flash<<<1024, 64, 0, stream>>>(Qh, Kh, VTt, Cur, Xh, out, nw, nb,
                                       (l == 2) ? 1 : 0, h);
    }
  }
}

// Round 12
// 938.981 us; speedup vs baseline: 1.2111x; 1.2111x over previous
//
#include <hip/hip_runtime.h>

typedef __attribute__((ext_vector_type(8))) short short8;
typedef __attribute__((ext_vector_type(4))) float f32x4;
typedef __attribute__((ext_vector_type(4))) unsigned short us4v;
typedef unsigned short ushort_t;
typedef unsigned int uint_t;

#define BB 4
#define T_ 1024
#define T2 2048
#define DD 256
#define DIN 512
#define NMARK 64
#define LNEPS 1e-5f
#define KDIV (-0.035977892078032f)

__device__ __forceinline__ ushort_t f2bf(float f) {
  unsigned int u = __float_as_uint(f);
  unsigned int r = (u + 0x7fffu + ((u >> 16) & 1u)) >> 16;
  return (ushort_t)r;
}
__device__ __forceinline__ uint_t pack2(float a, float b) {
  return (uint_t)f2bf(a) | ((uint_t)f2bf(b) << 16);
}
__device__ __forceinline__ uint_t cvtpk(float lo, float hi) {
  uint_t r;
  asm("v_cvt_pk_bf16_f32 %0, %1, %2" : "=v"(r) : "v"(lo), "v"(hi));
  return r;
}

typedef const __attribute__((address_space(1))) unsigned int* as1cu32;
typedef __attribute__((address_space(3))) unsigned int* as3u32;
__device__ __forceinline__ void async_copy16(const void* g, void* l) {
  __builtin_amdgcn_global_load_lds((as1cu32)g, (as3u32)l, 16, 0, 0);
}

// ---------- init: type/time embeddings -> Xh (bf16), Cur = 0 ----------
__global__ __launch_bounds__(256) void k_init(const float* __restrict__ ev,
                                              const float* __restrict__ tm,
                                              const float* __restrict__ Wt,
                                              const float* __restrict__ bt,
                                              ushort_t* __restrict__ Xh,
                                              float* __restrict__ Cur) {
  const int btq = blockIdx.x;
  const int b = btq >> 10;
  const int t = btq & 1023;
  const int d = threadIdx.x;
  __shared__ float evs[NMARK];
  if (d < NMARK) evs[d] = ev[(size_t)btq * NMARK + d];
  __syncthreads();
  float s = bt[d];
#pragma unroll
  for (int m = 0; m < NMARK; ++m) s += evs[m] * Wt[m * DD + d];
  const float te_type = tanhf(s);
  const float tv = tm[btq];
  const int i = d >> 1;
  const float dv = expf((float)(2 * i) * KDIV);
  const float ang = tv * dv;
  const float te_time = (d & 1) ? cosf(ang) : sinf(ang);
  ushort_t* Xb = Xh + (size_t)b * T2 * DIN;
  const ushort_t tt = f2bf(te_time);
  Xb[(size_t)t * DIN + d] = f2bf(te_type);
  Xb[(size_t)t * DIN + DD + d] = tt;
  Xb[(size_t)(T_ + t) * DIN + d] = 0;
  Xb[(size_t)(T_ + t) * DIN + DD + d] = tt;
  Cur[((size_t)b * T_ + t) * DD + d] = 0.0f;
}

// ---------- weight transpose: W[hl][k][n] f32 -> WT[mat][n][k] bf16 ----------
__global__ __launch_bounds__(256) void k_transW(const float* __restrict__ Wq,
                                                const float* __restrict__ Wk,
                                                const float* __restrict__ Wv,
                                                ushort_t* __restrict__ WT) {
  const int mi = blockIdx.x;
  const int wsel = mi / 12, hl = mi % 12;
  const float* W = ((wsel == 0) ? Wq : (wsel == 1) ? Wk : Wv) + (size_t)hl * DIN * DD;
  const int t = blockIdx.y;
  const int k0 = (t >> 2) * 64, n0 = (t & 3) * 64;
  __shared__ float Ts[64][65];
  const int tid = threadIdx.x;
#pragma unroll
  for (int i = 0; i < 16; ++i) {
    const int idx = tid + i * 256;
    const int r = idx >> 6, c = idx & 63;
    Ts[r][c] = W[(size_t)(k0 + r) * DD + n0 + c];
  }
  __syncthreads();
  ushort_t* D = WT + (size_t)mi * DD * DIN;
#pragma unroll
  for (int i = 0; i < 16; ++i) {
    const int idx = tid + i * 256;
    const int rn = idx >> 6, ck = idx & 63;
    D[(size_t)(n0 + rn) * DIN + k0 + ck] = f2bf(Ts[ck][rn]);
  }
}

// ---------- QKV GEMM; V written pi32-permuted into 32-wide TILES ----------
// VTt[b][tile32(64)][d(256)][32] bf16: 16KB contiguous per KV-tile.
__global__ __launch_bounds__(256) void k_qkv(const ushort_t* __restrict__ Xh,
                                             const ushort_t* __restrict__ WT,
                                             const float* __restrict__ bq,
                                             const float* __restrict__ bk,
                                             const float* __restrict__ bv,
                                             ushort_t* __restrict__ Qh,
                                             ushort_t* __restrict__ Kh,
                                             ushort_t* __restrict__ VTt,
                                             int hl) {
  const int m0 = blockIdx.x * 128;
  const int n0 = blockIdx.y * 128;
  const int wsel = blockIdx.z;
  const ushort_t* Bt = WT + ((size_t)(wsel * 12 + hl)) * DD * DIN + (size_t)n0 * DIN;
  const float* bias = (wsel == 0) ? bq : (wsel == 1) ? bk : bv;

  __shared__ ushort_t As[128 * 64];
  __shared__ ushort_t Bs[128 * 64];
  const int tid = threadIdx.x;
  const int w = tid >> 6, lane = tid & 63;
  const int wr = w >> 1, wc = w & 1;
  const int lr = lane & 15, kg = lane >> 4;

  f32x4 acc[4][4];
  const f32x4 z4 = {0.f, 0.f, 0.f, 0.f};
#pragma unroll
  for (int a = 0; a < 4; ++a)
#pragma unroll
    for (int c = 0; c < 4; ++c) acc[a][c] = z4;

  for (int k0 = 0; k0 < DIN; k0 += 64) {
#pragma unroll
    for (int i = 0; i < 4; ++i) {
      const int idx = tid + i * 256;
      const int row = idx >> 3, ch = idx & 7;
      const int db = row * 128 + ((ch * 16) ^ ((row & 7) << 4));
      uint4 va = *(const uint4*)&Xh[(size_t)(m0 + row) * DIN + k0 + ch * 8];
      *(uint4*)((char*)As + db) = va;
      uint4 vb = *(const uint4*)&Bt[(size_t)row * DIN + k0 + ch * 8];
      *(uint4*)((char*)Bs + db) = vb;
    }
    __syncthreads();
#pragma unroll
    for (int kk = 0; kk < 2; ++kk) {
      short8 af[4], bfr[4];
      const int cb = kk * 64 + kg * 16;
#pragma unroll
      for (int mi = 0; mi < 4; ++mi) {
        const int row = wr * 64 + mi * 16 + lr;
        af[mi] = *(const short8*)((const char*)As + row * 128 + (cb ^ ((row & 7) << 4)));
      }
#pragma unroll
      for (int ni = 0; ni < 4; ++ni) {
        const int row = wc * 64 + ni * 16 + lr;
        bfr[ni] = *(const short8*)((const char*)Bs + row * 128 + (cb ^ ((row & 7) << 4)));
      }
#pragma unroll
      for (int mi = 0; mi < 4; ++mi)
#pragma unroll
        for (int ni = 0; ni < 4; ++ni)
          acc[mi][ni] = __builtin_amdgcn_mfma_f32_16x16x32_bf16(af[mi], bfr[ni], acc[mi][ni], 0, 0, 0);
    }
    __syncthreads();
  }

  if (wsel < 2) {
    ushort_t* C = (wsel == 0) ? Qh : Kh;
#pragma unroll
    for (int mi = 0; mi < 4; ++mi)
#pragma unroll
      for (int ni = 0; ni < 4; ++ni) {
        const int col = n0 + wc * 64 + ni * 16 + lr;
        const float bcol = bias[col];
        const int rbase = m0 + wr * 64 + mi * 16 + kg * 4;
#pragma unroll
        for (int r = 0; r < 4; ++r)
          C[(size_t)(rbase + r) * DD + col] = f2bf(acc[mi][ni][r] + bcol);
      }
  } else {
    const int b2 = m0 >> 11;
    const int t0q = m0 & 2047;
#pragma unroll
    for (int mi = 0; mi < 4; ++mi)
#pragma unroll
      for (int ni = 0; ni < 4; ++ni) {
        const int col = n0 + wc * 64 + ni * 16 + lr;
        const float bcol = bias[col];
        const int t32 = (t0q >> 5) + wr * 2 + (mi >> 1);
        const int jloc = kg * 8 + (mi & 1) * 4;
        uint2 pk;
        pk.x = pack2(acc[mi][ni][0] + bcol, acc[mi][ni][1] + bcol);
        pk.y = pack2(acc[mi][ni][2] + bcol, acc[mi][ni][3] + bcol);
        *(uint2*)(VTt + ((size_t)(b2 * 64 + t32)) * (DD * 32) + col * 32 + jloc) = pk;
      }
  }
}

// ---------- flash: 4 waves = (rowsub 0/1) x (parity 0/1), shared staging ----------
// grid 256 x 256. hb = bx&1, b = (bx>>1)&3 (XCD-affine), tc = 31-(bx>>3).
// LDS: 3 x (K 16KB + V 16KB) triple buffer | merge scalars @98304.
__global__ __launch_bounds__(256, 1) void k_flash(const ushort_t* __restrict__ Qh,
                                                  const ushort_t* __restrict__ Kh,
                                                  const ushort_t* __restrict__ VTt,
                                                  float* __restrict__ Cur,
                                                  ushort_t* __restrict__ Xh,
                                                  float* __restrict__ out,
                                                  const float* __restrict__ nw,
                                                  const float* __restrict__ nb,
                                                  int lastLayer, int h) {
  __shared__ char lds[98816];
  float* mArr = (float*)(lds + 98304);   // [4][16]
  float* lArr = mArr + 64;               // [4][16]

  const int tid = threadIdx.x;
  const int bx = blockIdx.x;
  const int hb = bx & 1;
  const int b = (bx >> 1) & 3;
  const int tc = 31 - (bx >> 3);         // heavy chunks first
  const int t0 = tc * 32;
  const int nc = tc + 1;
  const int nt = nc + hb;
  const int dt = 32 + tc;

  const int w = tid >> 6, lane = tid & 63;
  const int parity = w >> 1, rowsub = w & 1;
  const int kg = lane >> 4, lr = lane & 15;
  const int tloc = rowsub * 16 + lr;
  const int trow = t0 + tloc;
  const int r0 = (hb ? T_ : 0) + trow;
  const size_t bT2 = (size_t)b * T2;

  short8 qf[8];
  {
    const ushort_t* qb = Qh + (bT2 + r0) * DD + kg * 8;
#pragma unroll
    for (int kk = 0; kk < 8; ++kk) qf[kk] = *(const short8*)(qb + kk * 32);
  }

  const f32x4 z4 = {0.f, 0.f, 0.f, 0.f};
  f32x4 acc_o[16];
#pragma unroll
  for (int db = 0; db < 16; ++db) acc_o[db] = z4;
  float m_run = -1e30f, l_run = 0.f;

  // 4 waves co-stage one 32KB tile: wave w issues chunks c = w*4..w*4+3 (K+V)
#define STAGE(BUF, TILE)                                                                  \
  {                                                                                       \
    const int _t = (TILE);                                                                \
    const char* Vt = (const char*)VTt + ((size_t)(b * 64 + _t)) * 16384;                  \
    _Pragma("unroll") for (int s = 0; s < 4; ++s) {                                       \
      const int c = w * 4 + s;                                                            \
      const int row2 = (c << 1) | (lane >> 5);                                            \
      const int cc2 = lane & 31;                                                          \
      async_copy16((const char*)Kh + ((bT2 + _t * 32 + row2) * DD) * 2 +                  \
                       ((cc2 * 16) ^ ((row2 & 7) << 4)),                                  \
                   lds + (BUF) * 32768 + c * 1024);                                       \
      async_copy16(Vt + c * 1024 + lane * 16,                                             \
                   lds + (BUF) * 32768 + 16384 + c * 1024);                               \
    }                                                                                     \
  }

  STAGE(0, 0);
  if (nt > 1) STAGE(1, (1 < nc) ? 1 : dt);

  union U8 { uint4 u; short8 s; };
  int cur = 0;

  for (int kt = 0; kt < nt; ++kt) {
    if (kt + 1 < nt) {
      asm volatile("s_waitcnt vmcnt(8)" ::: "memory");   // tile kt resident
    } else {
      asm volatile("s_waitcnt vmcnt(0)" ::: "memory");
    }
    __builtin_amdgcn_sched_barrier(0);
    __builtin_amdgcn_s_barrier();                        // staged + all past kt-1
    __builtin_amdgcn_sched_barrier(0);

    {
      const int ki = kt + 2;
      if (ki < nt) {
        const int ib = (cur == 0) ? 2 : cur - 1;         // (cur+2)%3
        STAGE(ib, (ki < nc) ? ki : dt);
      }
    }

    if ((kt & 1) == parity) {
      const int tile = (kt < nc) ? kt : dt;
      const bool isDiag = (kt >= nc);
      const char* KsC = lds + cur * 32768;
      const char* VsC = KsC + 16384;

      // QK^T (swapped): S^T[j = tile*32 + jb*16 + kg*4 + r][q = lr]
      f32x4 sa[2];
      __builtin_amdgcn_s_setprio(1);
#pragma unroll
      for (int jb = 0; jb < 2; ++jb) {
        sa[jb] = z4;
        const int rowj = jb * 16 + lr;
        const int base = rowj * 512;
        const int swj = (rowj & 7) << 4;
#pragma unroll
        for (int kk = 0; kk < 8; ++kk) {
          short8 kf = *(const short8*)(KsC + base + ((kk * 64 + kg * 16) ^ swj));
          sa[jb] = __builtin_amdgcn_mfma_f32_16x16x32_bf16(kf, qf[kk], sa[jb], 0, 0, 0);
        }
      }
      __builtin_amdgcn_s_setprio(0);

      // mask + scale + online softmax with defer-max
      float sv[8];
      float tmax = -1e30f;
#pragma unroll
      for (int jb = 0; jb < 2; ++jb)
#pragma unroll
        for (int r = 0; r < 4; ++r) {
          const int jl = jb * 16 + kg * 4 + r;
          const bool valid = isDiag ? (jl == tloc) : ((tile * 32 + jl) < trow);
          const float x = valid ? sa[jb][r] * 0.0625f : -1e30f;
          sv[jb * 4 + r] = x;
          tmax = fmaxf(tmax, x);
        }
      tmax = fmaxf(tmax, __shfl_xor(tmax, 16, 64));
      tmax = fmaxf(tmax, __shfl_xor(tmax, 32, 64));
      if (tmax > m_run + 8.0f) {
        const float fac = __expf(m_run - tmax);
        m_run = tmax;
        l_run *= fac;
#pragma unroll
        for (int db = 0; db < 16; ++db) acc_o[db] *= fac;
      }
      float p[8];
      float psum = 0.f;
#pragma unroll
      for (int e = 0; e < 8; ++e) {
        const float pe = (sv[e] > -1e29f) ? __expf(sv[e] - m_run) : 0.0f;
        p[e] = pe;
        psum += pe;
      }
      psum += __shfl_xor(psum, 16, 64);
      psum += __shfl_xor(psum, 32, 64);
      l_run += psum;

      U8 pf;
      pf.u.x = cvtpk(p[0], p[1]);
      pf.u.y = cvtpk(p[2], p[3]);
      pf.u.z = cvtpk(p[4], p[5]);
      pf.u.w = cvtpk(p[6], p[7]);

      __builtin_amdgcn_s_setprio(1);
#pragma unroll
      for (int db = 0; db < 16; ++db) {
        U8 vf;
        vf.u = *(const uint4*)(VsC + (db * 16 + lr) * 64 + kg * 16);
        acc_o[db] = __builtin_amdgcn_mfma_f32_16x16x32_bf16(vf.s, pf.s, acc_o[db], 0, 0, 0);
      }
      __builtin_amdgcn_s_setprio(0);
    }

    cur = (cur == 2) ? 0 : cur + 1;
  }
#undef STAGE

  // ---------- merge parity pairs (w and w^2 share q-rows) ----------
  __syncthreads();
  if (kg == 0) { mArr[w * 16 + lr] = m_run; lArr[w * 16 + lr] = l_run; }
  if (w >= 2) {   // parity-1 waves dump partials: Om[rowsub][16 rows][256 d]
    char* ob = lds + rowsub * 16384 + lr * 1024 + kg * 256;
#pragma unroll
    for (int db = 0; db < 16; ++db) *(f32x4*)(ob + db * 16) = acc_o[db];
  }
  __syncthreads();

  if (w >= 2) {
    // ---------- row0 mean-V fold (waves 2,3 of 4 lightest top blocks) ----------
    if (!hb && tc < 4) {
      const int col = tc * 64 + (w - 2) * 32 + (lane & 31);
      const int half = lane >> 5;
      float s = 0.f;
      for (int tl = half * 32; tl < half * 32 + 32; ++tl) {
        const ushort_t* vp = VTt + ((size_t)(b * 64 + tl)) * 8192 + col * 32;
#pragma unroll
        for (int j = 0; j < 32; j += 8) {
          uint4 v = *(const uint4*)(vp + j);
          const uint_t vs[4] = {v.x, v.y, v.z, v.w};
#pragma unroll
          for (int q = 0; q < 4; ++q) {
            s += __uint_as_float(vs[q] << 16);
            s += __uint_as_float(vs[q] & 0xffff0000u);
          }
        }
      }
      s += __shfl_xor(s, 32, 64);
      if (lane < 32) Xh[bT2 * DIN + col] = f2bf(s * (1.0f / 2048.0f));
    }
    return;
  }

  // waves 0,1: combine with partner (w+2), then epilogue
  {
    const float m_p = mArr[(w + 2) * 16 + lr];
    const float l_p = lArr[(w + 2) * 16 + lr];
    const float mstar = fmaxf(m_run, m_p);
    const float fs = __expf(m_run - mstar);
    const float fp = __expf(m_p - mstar);
    l_run = l_run * fs + l_p * fp;
    const char* ob = lds + rowsub * 16384 + lr * 1024 + kg * 256;
#pragma unroll
    for (int db = 0; db < 16; ++db) {
      f32x4 o2 = *(const f32x4*)(ob + db * 16);
#pragma unroll
      for (int r = 0; r < 4; ++r) acc_o[db][r] = acc_o[db][r] * fs + o2[r] * fp;
    }
  }

  const float oinv = 1.0f / l_run;   // t==0 (top): l==0 -> store skipped

  if (!hb) {
    if (trow != 0) {
      ushort_t* xp = Xh + (bT2 + trow) * DIN + kg * 4;
#pragma unroll
      for (int db = 0; db < 16; ++db) {
        us4v o;
#pragma unroll
        for (int r = 0; r < 4; ++r) o[r] = f2bf(acc_o[db][r] * oinv);
        *(us4v*)(xp + db * 16) = o;
      }
    }
  } else {
    float* cp = Cur + ((size_t)b * T_ + trow) * DD + kg * 4;
    float s1 = 0.f, s2 = 0.f;
#pragma unroll
    for (int db = 0; db < 16; ++db) {
      f32x4 c4 = *(const f32x4*)(cp + db * 16);
#pragma unroll
      for (int r = 0; r < 4; ++r) {
        const float x = tanhf(acc_o[db][r] * oinv) + c4[r];
        acc_o[db][r] = x;
        s1 += x;
        s2 += x * x;
      }
    }
    s1 += __shfl_xor(s1, 16, 64); s1 += __shfl_xor(s1, 32, 64);
    s2 += __shfl_xor(s2, 16, 64); s2 += __shfl_xor(s2, 32, 64);
    const float mean = s1 * (1.0f / 256.0f);
    const float var = s2 * (1.0f / 256.0f) - mean * mean;
    const float rinv = rsqrtf(var + LNEPS);
    ushort_t* xp = Xh + (bT2 + T_ + trow) * DIN + kg * 4;
    if (lastLayer) {
      float* op = out + ((size_t)b * T_ + trow) * (DD * 4) + h * DD + kg * 4;
      const us4v zz = {0, 0, 0, 0};
      const f32x4 zf = {0.f, 0.f, 0.f, 0.f};
#pragma unroll
      for (int db = 0; db < 16; ++db) {
        f32x4 w4 = *(const f32x4*)&nw[db * 16 + kg * 4];
        f32x4 b4 = *(const f32x4*)&nb[db * 16 + kg * 4];
        f32x4 y;
#pragma unroll
        for (int r = 0; r < 4; ++r) y[r] = (acc_o[db][r] - mean) * rinv * w4[r] + b4[r];
        *(f32x4*)(op + db * 16) = y;
        *(f32x4*)(cp + db * 16) = zf;
        *(us4v*)(xp + db * 16) = zz;
      }
    } else {
#pragma unroll
      for (int db = 0; db < 16; ++db) {
        f32x4 w4 = *(const f32x4*)&nw[db * 16 + kg * 4];
        f32x4 b4 = *(const f32x4*)&nb[db * 16 + kg * 4];
        f32x4 y;
        us4v yh;
#pragma unroll
        for (int r = 0; r < 4; ++r) {
          y[r] = (acc_o[db][r] - mean) * rinv * w4[r] + b4[r];
          yh[r] = f2bf(y[r]);
        }
        *(f32x4*)(cp + db * 16) = y;
        *(us4v*)(xp + db * 16) = yh;
      }
    }
  }
}

extern "C" void kernel_launch(void* const* d_in, const int* in_sizes, int n_in,
                              void* d_out, int out_size, void* d_ws, size_t ws_size,
                              hipStream_t stream) {
  const float* ev = (const float*)d_in[0];
  const float* tm = (const float*)d_in[1];
  const float* Wt = (const float*)d_in[3];
  const float* bt = (const float*)d_in[4];
  const float* Wq = (const float*)d_in[5];
  const float* bq = (const float*)d_in[6];
  const float* Wk = (const float*)d_in[7];
  const float* bk = (const float*)d_in[8];
  const float* Wv = (const float*)d_in[9];
  const float* bv = (const float*)d_in[10];
  const float* nw = (const float*)d_in[11];
  const float* nb = (const float*)d_in[12];
  float* out = (float*)d_out;

  char* p = (char*)d_ws;
  ushort_t* Xh  = (ushort_t*)p; p += (size_t)BB * T2 * DIN * 2;   // 8.39 MB
  ushort_t* Qh  = (ushort_t*)p; p += (size_t)BB * T2 * DD * 2;    // 4.19 MB
  ushort_t* Kh  = (ushort_t*)p; p += (size_t)BB * T2 * DD * 2;
  ushort_t* VTt = (ushort_t*)p; p += (size_t)BB * T2 * DD * 2;    // pi32-tiled V
  float* Cur    = (float*)p;    p += (size_t)BB * T_ * DD * 4;    // 4.19 MB
  ushort_t* WT  = (ushort_t*)p;                                   // 9.44 MB

  k_init<<<BB * T_, 256, 0, stream>>>(ev, tm, Wt, bt, Xh, Cur);
  k_transW<<<dim3(36, 32), 256, 0, stream>>>(Wq, Wk, Wv, WT);

  for (int h = 0; h < 4; ++h) {
    for (int l = 0; l < 3; ++l) {
      const int hl = h * 3 + l;
      const size_t boff = (size_t)hl * DD;
      k_qkv<<<dim3(64, 2, 3), 256, 0, stream>>>(Xh, WT, bq + boff, bk + boff, bv + boff,
                                                Qh, Kh, VTt, hl);
      k_flash<<<256, 256, 0, stream>>>(Qh, Kh, VTt, Cur, Xh, out, nw, nb,
                                       (l == 2) ? 1 : 0, h);
    }
  }
}